// Round 9
// baseline (303.568 us; speedup 1.0000x reference)
//
#include <hip/hip_runtime.h>
#include <hip/hip_bf16.h>
#include <cstdint>
#include <cstddef>

// GATv2Conv forward, N=100000, E=1.6M, IN=128, H=4, C=32 (H*C=128).
//
// xl/xr are stored in a PERMUTED channel order chosen so the MFMA D-layout
// packs pairs: storage slot j' = h*32 + m16*2 + b  holds logical col
// (2h+b)*16 + m16.  gemm stores uint pairs (coalesced); agg reads uint2 per
// lane exactly as before but uses attP/biasP permuted to match (attP also
// pre-scaled by log2(e) so w = exp2f(p) = exp(p) with no mul).
//
// Pipeline:
//   1) histW_k : 16 ranges x 32 chunks (1024-thr, LDS hist, no global atomics)
//                + 1 block: W->bf16 Wt transpose, attP/biasP permute.
//   2) mfma_gemm_k : xl=x@Wl, xr=x@Wr via v_mfma_f32_16x16x32_bf16, paired-store
//                epilogue into permuted layout.
//   3) scanA_k (g colsum fused) -> scanB_k -> cbase_k (scanC fused).
//   4) scat_k  : LDS-cursor scatter, range<->XCD affinity.
//   5) agg_k   : one wave per dst node, 8 edges/iter, exp2-softmax w/o max-sub.

#define NEG_SLOPE 0.2f
#define EPS_F 1e-16f
#define NRANGE 16
#define NCHUNK 32
#define SORT_B 1024
#define MAX_RSZ 6272    // >= ceil(N/NRANGE)=6250; LDS = 25 KB

typedef __attribute__((ext_vector_type(8))) short bf16x8;
typedef __attribute__((ext_vector_type(4))) float f32x4;

static __device__ __forceinline__ unsigned f2bf(float f) {
    unsigned u = __float_as_uint(f);
    return (u + 0x7fffu + ((u >> 16) & 1u)) >> 16;   // RNE
}

// ------------- LDS-histogram pass + W transpose + att/bias permute -------------
__global__ __launch_bounds__(SORT_B) void histW_k(const int* __restrict__ dst, int E, int N,
                                                  int rsz, int chunk_e,
                                                  unsigned* __restrict__ g,
                                                  const float* __restrict__ Wl,
                                                  const float* __restrict__ Wr,
                                                  unsigned short* __restrict__ Wtl,
                                                  unsigned short* __restrict__ Wtr,
                                                  const float* __restrict__ att,
                                                  const float* __restrict__ bias,
                                                  float* __restrict__ attP,
                                                  float* __restrict__ biasP) {
    if (blockIdx.x == NRANGE * NCHUNK) {
        for (int mat = 0; mat < 2; ++mat) {
            const float* W = mat ? Wr : Wl;
            unsigned short* Wt = mat ? Wtr : Wtl;
            for (int i = 0; i < 16; ++i) {
                int idx = (int)threadIdx.x + i * SORT_B;
                int k = idx >> 7, n = idx & 127;
                Wt[n * 128 + k] = (unsigned short)f2bf(W[idx]);
            }
        }
        if (threadIdx.x < 128) {
            int j = threadIdx.x;                     // storage slot
            int h = j >> 5, r = j & 31;
            int m16 = r >> 1, b = r & 1;
            int col = (2 * h + b) * 16 + m16;        // logical channel
            attP[j]  = att[col] * 1.44269504088896f; // fold log2(e) into att
            biasP[j] = bias[col];
        }
        return;
    }
    __shared__ unsigned lcnt[MAX_RSZ];
    const int r = blockIdx.x & (NRANGE - 1);
    const int c = blockIdx.x >> 4;
    const unsigned r_lo = (unsigned)(r * rsz);
    const int e0 = c * chunk_e;
    const int e1 = min(e0 + chunk_e, E);

    for (int i = threadIdx.x; i < rsz; i += SORT_B) lcnt[i] = 0u;
    __syncthreads();
    for (int e = e0 + (int)threadIdx.x; e < e1; e += SORT_B) {
        unsigned dd = (unsigned)dst[e] - r_lo;
        if (dd < (unsigned)rsz) atomicAdd(&lcnt[dd], 1u);   // LDS atomic
    }
    __syncthreads();
    unsigned* gc = g + (size_t)c * N + r_lo;
    int lim = min(rsz, N - (int)r_lo);
    for (int i = threadIdx.x; i < lim; i += SORT_B) gc[i] = lcnt[i];
}

// ------------- MFMA GEMM with paired-store epilogue (permuted layout) -------------
#define LROW 136
__global__ __launch_bounds__(256) void mfma_gemm_k(const float* __restrict__ A,
                                                   const unsigned short* __restrict__ Wtl,
                                                   const unsigned short* __restrict__ Wtr,
                                                   unsigned* __restrict__ xl32,
                                                   unsigned* __restrict__ xr32,
                                                   int nrows) {
    __shared__ unsigned short As[64 * LROW];
    __shared__ unsigned short Ws[128 * LROW];
    const int tid = threadIdx.x;
    const int wave = tid >> 6, lane = tid & 63;
    const int quad = lane >> 4, m16 = lane & 15;
    const int row0 = blockIdx.x * 64;

#pragma unroll
    for (int i = 0; i < 8; ++i) {
        int idx = tid + i * 256;
        int r = idx >> 5, c4 = idx & 31;
        int gr = row0 + r;
        gr = gr < nrows ? gr : nrows - 1;
        float4 v = *(const float4*)(A + (size_t)gr * 128 + c4 * 4);
        ushort4 b;
        b.x = (unsigned short)f2bf(v.x);
        b.y = (unsigned short)f2bf(v.y);
        b.z = (unsigned short)f2bf(v.z);
        b.w = (unsigned short)f2bf(v.w);
        *(ushort4*)(&As[r * LROW + c4 * 4]) = b;
    }
#pragma unroll
    for (int i = 0; i < 8; ++i) {
        int idx = tid + i * 256;
        int n = idx >> 4, kq = idx & 15;
        *(uint4*)(&Ws[n * LROW + kq * 8]) = *(const uint4*)(Wtl + n * 128 + kq * 8);
    }
    __syncthreads();

    bf16x8 af[4];
#pragma unroll
    for (int ks = 0; ks < 4; ++ks)
        af[ks] = *(const bf16x8*)(&As[(wave * 16 + m16) * LROW + ks * 32 + quad * 8]);

    f32x4 acc[8];
#pragma unroll
    for (int ct = 0; ct < 8; ++ct) acc[ct] = (f32x4){0.f, 0.f, 0.f, 0.f};
#pragma unroll
    for (int ct = 0; ct < 8; ++ct)
#pragma unroll
        for (int ks = 0; ks < 4; ++ks) {
            bf16x8 bf = *(const bf16x8*)(&Ws[(ct * 16 + m16) * LROW + ks * 32 + quad * 8]);
            acc[ct] = __builtin_amdgcn_mfma_f32_16x16x32_bf16(af[ks], bf, acc[ct], 0, 0, 0);
        }
    // paired-store epilogue: slot-pair (h, m16) <- (acc[2h][r], acc[2h+1][r])
#pragma unroll
    for (int r = 0; r < 4; ++r) {
        int grow = row0 + wave * 16 + quad * 4 + r;
        if (grow < nrows)
#pragma unroll
            for (int h = 0; h < 4; ++h)
                xl32[(size_t)grow * 64 + h * 16 + m16] =
                    f2bf(acc[2 * h][r]) | (f2bf(acc[2 * h + 1][r]) << 16);
    }

    __syncthreads();
#pragma unroll
    for (int i = 0; i < 8; ++i) {
        int idx = tid + i * 256;
        int n = idx >> 4, kq = idx & 15;
        *(uint4*)(&Ws[n * LROW + kq * 8]) = *(const uint4*)(Wtr + n * 128 + kq * 8);
    }
    __syncthreads();

#pragma unroll
    for (int ct = 0; ct < 8; ++ct) acc[ct] = (f32x4){0.f, 0.f, 0.f, 0.f};
#pragma unroll
    for (int ct = 0; ct < 8; ++ct)
#pragma unroll
        for (int ks = 0; ks < 4; ++ks) {
            bf16x8 bf = *(const bf16x8*)(&Ws[(ct * 16 + m16) * LROW + ks * 32 + quad * 8]);
            acc[ct] = __builtin_amdgcn_mfma_f32_16x16x32_bf16(af[ks], bf, acc[ct], 0, 0, 0);
        }
#pragma unroll
    for (int r = 0; r < 4; ++r) {
        int grow = row0 + wave * 16 + quad * 4 + r;
        if (grow < nrows)
#pragma unroll
            for (int h = 0; h < 4; ++h)
                xr32[(size_t)grow * 64 + h * 16 + m16] =
                    f2bf(acc[2 * h][r]) | (f2bf(acc[2 * h + 1][r]) << 16);
    }
}

// ---------------- scanA (colsum fused) ----------------
#define SCAN_B 256
__global__ __launch_bounds__(SCAN_B) void scanA_k(const unsigned* __restrict__ g, int n,
                                                  int* __restrict__ row_start,
                                                  int* __restrict__ bsum) {
    const int tid = threadIdx.x, lane = tid & 63, wid = tid >> 6;
    const int d = blockIdx.x * SCAN_B + tid;
    int v = 0;
    if (d < n) {
        unsigned s = 0;
#pragma unroll
        for (int c = 0; c < NCHUNK; ++c) s += g[(size_t)c * n + d];
        v = (int)s;
    }
    int inc = v;
#pragma unroll
    for (int dd = 1; dd < 64; dd <<= 1) {
        int t = __shfl_up(inc, dd);
        if (lane >= dd) inc += t;
    }
    __shared__ int wsum[SCAN_B / 64];
    if (lane == 63) wsum[wid] = inc;
    __syncthreads();
    int add = 0;
    for (int w = 0; w < wid; ++w) add += wsum[w];
    inc += add;
    if (d < n) row_start[d] = inc - v;
    if (tid == SCAN_B - 1) bsum[blockIdx.x] = inc;
}

__global__ __launch_bounds__(512) void scanB_k(int* __restrict__ bsum, int nb) {
    const int tid = threadIdx.x, lane = tid & 63, wid = tid >> 6;
    int v = (tid < nb) ? bsum[tid] : 0;
    int inc = v;
#pragma unroll
    for (int d = 1; d < 64; d <<= 1) {
        int t = __shfl_up(inc, d);
        if (lane >= d) inc += t;
    }
    __shared__ int wsum[8];
    if (lane == 63) wsum[wid] = inc;
    __syncthreads();
    int add = 0;
    for (int w = 0; w < wid; ++w) add += wsum[w];
    inc += add;
    if (tid < nb) bsum[tid] = inc - v;
}

// ---------------- cbase (row_start finalize + scanC fused) ----------------
__global__ __launch_bounds__(SCAN_B) void cbase_k(const unsigned* __restrict__ g,
                                                  const int* __restrict__ bsum,
                                                  int* __restrict__ row_start, int N, int E,
                                                  unsigned* __restrict__ base,
                                                  int* __restrict__ src_sorted) {
    const int d = blockIdx.x * SCAN_B + threadIdx.x;
    if (d < N) {
        int rs = row_start[d] + bsum[blockIdx.x];
        row_start[d] = rs;
        unsigned run = (unsigned)rs;
#pragma unroll
        for (int c = 0; c < NCHUNK; ++c) {
            base[(size_t)c * N + d] = run;
            run += g[(size_t)c * N + d];
        }
    }
    if (d == 0) row_start[N] = E;
    if (blockIdx.x == 0 && threadIdx.x < 8) src_sorted[E + threadIdx.x] = 0;
}

// ------------- scatter via LDS cursors (no global atomics) -------------
__global__ __launch_bounds__(SORT_B) void scat_k(const int* __restrict__ src,
                                                 const int* __restrict__ dst, int E, int N,
                                                 int rsz, int chunk_e,
                                                 const unsigned* __restrict__ base,
                                                 int* __restrict__ src_sorted) {
    __shared__ unsigned lcur[MAX_RSZ];
    const int r = blockIdx.x & (NRANGE - 1);
    const int c = blockIdx.x >> 4;
    const unsigned r_lo = (unsigned)(r * rsz);
    const int e0 = c * chunk_e;
    const int e1 = min(e0 + chunk_e, E);

    const unsigned* bc = base + (size_t)c * N + r_lo;
    int lim = min(rsz, N - (int)r_lo);
    for (int i = threadIdx.x; i < lim; i += SORT_B) lcur[i] = bc[i];
    __syncthreads();

    for (int e = e0 + (int)threadIdx.x; e < e1; e += SORT_B) {
        unsigned dd = (unsigned)dst[e] - r_lo;
        if (dd < (unsigned)rsz) {
            unsigned pos = atomicAdd(&lcur[dd], 1u);   // LDS atomic
            src_sorted[pos] = src[e];
        }
    }
}

// ---------------- aggregation: one wave per dst node, 8 edges/iter ----------------
// Permuted storage: lane idx reads slots idx*4..+3 (head h = idx>>3); output
// cols for (t=0..3): c0=32h+2*(idx&7) -> {t0,t2} at c0,c0+1; {t1,t3} at +16.
__global__ __launch_bounds__(256) void agg_k(const unsigned* __restrict__ xlb,
                                             const unsigned* __restrict__ xrb,
                                             const float* __restrict__ attP,
                                             const float* __restrict__ biasP,
                                             const int* __restrict__ row_start,
                                             const int* __restrict__ src_sorted,
                                             int n, float* __restrict__ out) {
    const int wave = threadIdx.x >> 6;
    const int lane = threadIdx.x & 63;
    const int i = blockIdx.x * 4 + wave;
    if (i >= n) return;

    const int idx  = lane & 31;
    const int half = lane >> 5;

    uint2 xr2 = *(const uint2*)(xrb + (size_t)i * 64 + idx * 2);
    const float xr0 = __uint_as_float(xr2.x << 16);
    const float xr1 = __uint_as_float(xr2.x & 0xffff0000u);
    const float xr2f = __uint_as_float(xr2.y << 16);
    const float xr3 = __uint_as_float(xr2.y & 0xffff0000u);
    const float4 at4 = *(const float4*)(attP + idx * 4);

    const int k0 = row_start[i];
    const int k1 = row_start[i + 1];

    float l = 0.f, A0 = 0.f, A1 = 0.f, A2 = 0.f, A3 = 0.f;
    const char* xlbc = (const char*)xlb;
    const unsigned lane_off = (unsigned)(idx << 3);

    for (int k = k0; k < k1; k += 8) {
        const int kb = k + 4 * half;
        int s[4];
#pragma unroll
        for (int u = 0; u < 4; ++u) s[u] = src_sorted[kb + u];
        uint2 v[4];
#pragma unroll
        for (int u = 0; u < 4; ++u) {
            unsigned off = ((unsigned)s[u] << 8) + lane_off;   // s*256 + idx*8 bytes
            v[u] = *(const uint2*)(xlbc + off);
        }
#pragma unroll
        for (int u = 0; u < 4; ++u) {
            float x0 = __uint_as_float(v[u].x << 16);
            float x1 = __uint_as_float(v[u].x & 0xffff0000u);
            float x2 = __uint_as_float(v[u].y << 16);
            float x3 = __uint_as_float(v[u].y & 0xffff0000u);
            float h0 = x0 + xr0, h1 = x1 + xr1, h2 = x2 + xr2f, h3 = x3 + xr3;
            h0 = fmaxf(h0, NEG_SLOPE * h0);
            h1 = fmaxf(h1, NEG_SLOPE * h1);
            h2 = fmaxf(h2, NEG_SLOPE * h2);
            h3 = fmaxf(h3, NEG_SLOPE * h3);
            float p = fmaf(at4.x, h0, at4.y * h1) + fmaf(at4.z, h2, at4.w * h3);
            p += __shfl_xor(p, 1);
            p += __shfl_xor(p, 2);
            p += __shfl_xor(p, 4);
            float w = (kb + u < k1) ? exp2f(p) : 0.f;   // attP pre-scaled by log2e
            l += w;
            A0 = fmaf(w, x0, A0);
            A1 = fmaf(w, x1, A1);
            A2 = fmaf(w, x2, A2);
            A3 = fmaf(w, x3, A3);
        }
    }

    l  += __shfl_xor(l, 32);
    A0 += __shfl_xor(A0, 32);
    A1 += __shfl_xor(A1, 32);
    A2 += __shfl_xor(A2, 32);
    A3 += __shfl_xor(A3, 32);

    if (half == 0) {
        float inv = 1.f / (l + EPS_F);
        float4 b4 = *(const float4*)(biasP + idx * 4);
        const int h = idx >> 3;
        const int c0 = 32 * h + 2 * (idx & 7);
        float2 oA = {fmaf(A0, inv, b4.x), fmaf(A2, inv, b4.z)};   // cols c0, c0+1
        float2 oB = {fmaf(A1, inv, b4.y), fmaf(A3, inv, b4.w)};   // cols c0+16, c0+17
        *(float2*)(out + (size_t)i * 128 + c0) = oA;
        *(float2*)(out + (size_t)i * 128 + c0 + 16) = oB;
    }
}

// ---------------- launch ----------------
extern "C" void kernel_launch(void* const* d_in, const int* in_sizes, int n_in,
                              void* d_out, int out_size, void* d_ws, size_t ws_size,
                              hipStream_t stream) {
    const float* x    = (const float*)d_in[0];
    const int*   ei   = (const int*)d_in[1];
    const float* W_l  = (const float*)d_in[2];
    const float* W_r  = (const float*)d_in[3];
    const float* att  = (const float*)d_in[4];
    const float* bias = (const float*)d_in[5];
    float* out = (float*)d_out;

    const int N = in_sizes[0] / 128;
    const int E = in_sizes[1] / 2;
    const int* src = ei;
    const int* dst = ei + E;

    char* ws = (char*)d_ws;
    size_t off = 0;
    auto alloc = [&](size_t bytes) {
        void* p = ws + off;
        off += (bytes + 15) & ~(size_t)15;
        return p;
    };
    unsigned* xlb     = (unsigned*)alloc((size_t)N * 64 * 4);      // permuted bf16 [N][128]
    unsigned* xrb     = (unsigned*)alloc((size_t)N * 64 * 4);
    unsigned* g       = (unsigned*)alloc((size_t)NCHUNK * N * 4);  // 12.8 MB
    unsigned* base    = (unsigned*)alloc((size_t)NCHUNK * N * 4);  // 12.8 MB
    int* row_start    = (int*)alloc((size_t)(N + 1) * 4);
    const int nsb = (N + SCAN_B - 1) / SCAN_B;
    int* bsum         = (int*)alloc((size_t)nsb * 4);
    int* src_sorted   = (int*)alloc((size_t)(E + 8) * 4);
    unsigned short* Wtl = (unsigned short*)alloc((size_t)128 * 128 * 2);
    unsigned short* Wtr = (unsigned short*)alloc((size_t)128 * 128 * 2);
    float* attP       = (float*)alloc(128 * 4);
    float* biasP      = (float*)alloc(128 * 4);
    (void)ws_size;

    const int rsz = (N + NRANGE - 1) / NRANGE;          // 6250 (<= MAX_RSZ)
    const int chunk_e = (E + NCHUNK - 1) / NCHUNK;      // 50000

    histW_k<<<NRANGE * NCHUNK + 1, SORT_B, 0, stream>>>(dst, E, N, rsz, chunk_e, g,
                                                        W_l, W_r, Wtl, Wtr,
                                                        att, bias, attP, biasP);

    const int gB = (N + 63) / 64;
    mfma_gemm_k<<<gB, 256, 0, stream>>>(x, Wtl, Wtr, xlb, xrb, N);

    scanA_k<<<nsb, SCAN_B, 0, stream>>>(g, N, row_start, bsum);
    scanB_k<<<1, 512, 0, stream>>>(bsum, nsb);
    cbase_k<<<nsb, SCAN_B, 0, stream>>>(g, bsum, row_start, N, E, base, src_sorted);

    scat_k<<<NRANGE * NCHUNK, SORT_B, 0, stream>>>(src, dst, E, N, rsz, chunk_e,
                                                   base, src_sorted);

    agg_k<<<(N + 3) / 4, 256, 0, stream>>>(xlb, xrb, attP, biasP,
                                           row_start, src_sorted, N, out);
}